// Round 4
// baseline (144.438 us; speedup 1.0000x reference)
//
#include <hip/hip_runtime.h>
#include <math.h>

#define B   4
#define NF  4096
#define FM  32
#define H   128
#define NC  256
#define ROW (FM * H)      // 4096 floats per (b,n) row
#define CH  4             // chunks per row in the gather kernel
#define CHF (ROW / CH)    // 1024 floats per chunk = 256 float4
#define TILE 512          // member tile cached in LDS
#define NITEMS (NC * B * CH)   // 4096 work items for k_pool

// ---------------- Kernel A ---------------------------------------------------
// Blocks 0..4095: scores[b*NF+n] = dot(mean_f x, W) + b0   (one wave per row)
// Block 4096:     CSR of segment_ids -> offs[NC+1], perm[NF]; LPT order ord[];
//                 resets the k_pool ticket counter.
__global__ __launch_bounds__(256) void k_scores_csr(const float* __restrict__ x,
                                                    const float* __restrict__ W,
                                                    const float* __restrict__ bias,
                                                    const int* __restrict__ seg,
                                                    float* __restrict__ scores,
                                                    int* __restrict__ offs,
                                                    int* __restrict__ perm,
                                                    int* __restrict__ ord,
                                                    int* __restrict__ ticket) {
    const int t = threadIdx.x;

    if (blockIdx.x < B * NF / 4) {
        // ---- scores path: 4 waves/block, one row per wave ----
        const int wid  = t >> 6;
        const int lane = t & 63;
        const int row  = blockIdx.x * 4 + wid;
        const float4* rp = (const float4*)(x + (size_t)row * ROW);
        const float4  w4 = ((const float4*)W)[lane & 31];

        float acc = 0.f;
#pragma unroll
        for (int j = 0; j < 16; ++j) {
            float4 v = rp[lane + j * 64];
            acc += v.x * w4.x + v.y * w4.y + v.z * w4.z + v.w * w4.w;
        }
#pragma unroll
        for (int off = 32; off >= 1; off >>= 1)
            acc += __shfl_xor(acc, off, 64);
        if (lane == 0)
            scores[row] = acc * (1.0f / FM) + bias[0];
    } else {
        // ---- CSR + LPT path: one block, 256 threads (t == coarse id c) ----
        __shared__ int cnt[NC];
        __shared__ int sc[NC];
        __shared__ int cursor[NC];

        cnt[t] = 0;
        if (t == 0) *ticket = 0;
        __syncthreads();
#pragma unroll
        for (int i = 0; i < NF / 256; ++i)
            atomicAdd(&cnt[seg[t + i * 256]], 1);
        __syncthreads();

        // inclusive Hillis-Steele scan over 256 counts
        sc[t] = cnt[t];
        __syncthreads();
        for (int d = 1; d < NC; d <<= 1) {
            int v = (t >= d) ? sc[t - d] : 0;
            __syncthreads();
            sc[t] += v;
            __syncthreads();
        }
        const int ex = sc[t] - cnt[t];   // exclusive prefix
        offs[t]   = ex;
        cursor[t] = ex;
        if (t == 0) offs[NC] = NF;

        // LPT rank: rank[c] = #{j: cnt[j] > cnt[c]} + #{j < c: cnt[j] == cnt[c]}
        {
            const int my = cnt[t];
            int r = 0;
            for (int j = 0; j < NC; ++j) {
                const int cj = cnt[j];
                r += (cj > my) || (cj == my && j < t);
            }
            ord[r] = t;
        }
        __syncthreads();

#pragma unroll
        for (int i = 0; i < NF / 256; ++i) {
            const int n = t + i * 256;
            const int p = atomicAdd(&cursor[seg[n]], 1);
            perm[p] = n;
        }
    }
}

// ---------------- Kernel B ---------------------------------------------------
// Persistent blocks (2048 = 8/CU, fully resident) popping items from a global
// ticket. Item = (rank, b, chunk); rank-major pop order = LPT scheduling.
// Per item: wave-redundant shuffle stats (scores L2-resident, m ~ 16), then a
// weighted gather over the chunk's 1024 floats. Every x element read once.
__global__ __launch_bounds__(256) void k_pool(const float* __restrict__ x,
                                              const float* __restrict__ scores,
                                              const int* __restrict__ offs,
                                              const int* __restrict__ perm,
                                              const int* __restrict__ ord,
                                              int* __restrict__ ticket,
                                              float* __restrict__ out) {
    __shared__ int   sm_row[TILE];
    __shared__ float sm_w[TILE];
    __shared__ int   s_item;

    const int t    = threadIdx.x;
    const int lane = t & 63;

    for (;;) {
        __syncthreads();                       // protect s_item / LDS reuse
        if (t == 0) s_item = atomicAdd(ticket, 1);
        __syncthreads();
        const int item = s_item;
        if (item >= NITEMS) break;

        const int rank  = item >> 4;           // B*CH = 16 items per segment
        const int sub   = item & 15;
        const int b     = sub >> 2;
        const int chunk = sub & 3;
        const int c     = ord[rank];

        const int off0 = offs[c];
        const int m    = offs[c + 1] - off0;
        const float* sb = scores + b * NF;

        // ---- per-wave redundant segment stats (no barriers) ----
        float pm = -INFINITY;
        for (int k = lane; k < m; k += 64)
            pm = fmaxf(pm, sb[perm[off0 + k]]);
#pragma unroll
        for (int off = 32; off >= 1; off >>= 1)
            pm = fmaxf(pm, __shfl_xor(pm, off, 64));
        const float smax = pm;

        float ps = 0.f;
        for (int k = lane; k < m; k += 64)
            ps += expf(sb[perm[off0 + k]] - smax);
#pragma unroll
        for (int off = 32; off >= 1; off >>= 1)
            ps += __shfl_xor(ps, off, 64);
        const float rden = 1.0f / ps;

        // ---- weighted gather over this chunk ----
        float4 acc0 = make_float4(0.f, 0.f, 0.f, 0.f);
        float4 acc1 = make_float4(0.f, 0.f, 0.f, 0.f);
        const float4* xb = (const float4*)x + (size_t)b * NF * (ROW / 4)
                         + (size_t)chunk * (CHF / 4) + t;

        for (int base = 0; base < m; base += TILE) {
            const int mt = min(TILE, m - base);
            if (t < mt) {
                const int r = perm[off0 + base + t];
                sm_row[t] = r;
                sm_w[t]   = expf(sb[r] - smax) * rden;
            }
            __syncthreads();

            int k = 0;
            for (; k + 2 <= mt; k += 2) {
                const float w0 = sm_w[k];
                const float w1 = sm_w[k + 1];
                const float4 v0 = xb[(size_t)sm_row[k]     * (ROW / 4)];
                const float4 v1 = xb[(size_t)sm_row[k + 1] * (ROW / 4)];
                acc0.x += w0 * v0.x; acc0.y += w0 * v0.y;
                acc0.z += w0 * v0.z; acc0.w += w0 * v0.w;
                acc1.x += w1 * v1.x; acc1.y += w1 * v1.y;
                acc1.z += w1 * v1.z; acc1.w += w1 * v1.w;
            }
            if (k < mt) {
                const float w0 = sm_w[k];
                const float4 v0 = xb[(size_t)sm_row[k] * (ROW / 4)];
                acc0.x += w0 * v0.x; acc0.y += w0 * v0.y;
                acc0.z += w0 * v0.z; acc0.w += w0 * v0.w;
            }
            __syncthreads();
        }

        acc0.x += acc1.x; acc0.y += acc1.y;
        acc0.z += acc1.z; acc0.w += acc1.w;
        float4* op = (float4*)(out + (size_t)(b * NC + c) * ROW + (size_t)chunk * CHF);
        op[t] = acc0;
    }
}

// ---------------------------------------------------------------------------
extern "C" void kernel_launch(void* const* d_in, const int* in_sizes, int n_in,
                              void* d_out, int out_size, void* d_ws, size_t ws_size,
                              hipStream_t stream) {
    const float* x    = (const float*)d_in[0];
    const float* W    = (const float*)d_in[1];
    const float* bias = (const float*)d_in[2];
    const int*   seg  = (const int*)d_in[3];
    float*       out  = (float*)d_out;

    float* scores = (float*)d_ws;              // B*NF floats
    int*   offs   = (int*)(scores + B * NF);   // NC+1 ints
    int*   perm   = offs + (NC + 1);           // NF ints
    int*   ord    = perm + NF;                 // NC ints
    int*   ticket = ord + NC;                  // 1 int

    k_scores_csr<<<B * NF / 4 + 1, 256, 0, stream>>>(x, W, bias, seg, scores,
                                                     offs, perm, ord, ticket);
    k_pool      <<<2048,           256, 0, stream>>>(x, scores, offs, perm,
                                                     ord, ticket, out);
}

// Round 5
// 94.654 us; speedup vs baseline: 1.5260x; 1.5260x over previous
//
#include <hip/hip_runtime.h>
#include <math.h>

#define B   4
#define NF  4096
#define FM  32
#define H   128
#define NC  256
#define ROW (FM * H)      // 4096 floats per (b,n) row
#define CH  4             // chunks per row in the gather kernel
#define CHF (ROW / CH)    // 1024 floats per chunk = 256 float4
#define TILE 512          // member tile cached in LDS

// ---------------- Kernel A ---------------------------------------------------
// Blocks 0..4095: scores[b*NF+n] = dot(mean_f x, W) + b0   (one wave per row)
// Block 4096:     CSR of segment_ids -> offs[NC+1], perm[NF]; LPT order ord[]
//                 (rank -> coarse id, descending segment size).
__global__ __launch_bounds__(256) void k_scores_csr(const float* __restrict__ x,
                                                    const float* __restrict__ W,
                                                    const float* __restrict__ bias,
                                                    const int* __restrict__ seg,
                                                    float* __restrict__ scores,
                                                    int* __restrict__ offs,
                                                    int* __restrict__ perm,
                                                    int* __restrict__ ord) {
    const int t = threadIdx.x;

    if (blockIdx.x < B * NF / 4) {
        // ---- scores path: 4 waves/block, one row per wave ----
        const int wid  = t >> 6;
        const int lane = t & 63;
        const int row  = blockIdx.x * 4 + wid;
        const float4* rp = (const float4*)(x + (size_t)row * ROW);
        const float4  w4 = ((const float4*)W)[lane & 31];

        float acc = 0.f;
#pragma unroll
        for (int j = 0; j < 16; ++j) {
            float4 v = rp[lane + j * 64];
            acc += v.x * w4.x + v.y * w4.y + v.z * w4.z + v.w * w4.w;
        }
#pragma unroll
        for (int off = 32; off >= 1; off >>= 1)
            acc += __shfl_xor(acc, off, 64);
        if (lane == 0)
            scores[row] = acc * (1.0f / FM) + bias[0];
    } else {
        // ---- CSR + LPT path: one block, 256 threads (t == coarse id c) ----
        __shared__ int cnt[NC];
        __shared__ int sc[NC];
        __shared__ int cursor[NC];

        cnt[t] = 0;
        __syncthreads();
#pragma unroll
        for (int i = 0; i < NF / 256; ++i)
            atomicAdd(&cnt[seg[t + i * 256]], 1);
        __syncthreads();

        // inclusive Hillis-Steele scan over 256 counts
        sc[t] = cnt[t];
        __syncthreads();
        for (int d = 1; d < NC; d <<= 1) {
            int v = (t >= d) ? sc[t - d] : 0;
            __syncthreads();
            sc[t] += v;
            __syncthreads();
        }
        const int ex = sc[t] - cnt[t];   // exclusive prefix
        offs[t]   = ex;
        cursor[t] = ex;
        if (t == 0) offs[NC] = NF;

        // LPT rank: rank[c] = #{j: cnt[j] > cnt[c]} + #{j < c: cnt[j] == cnt[c]}
        {
            const int my = cnt[t];
            int r = 0;
            for (int j = 0; j < NC; ++j) {
                const int cj = cnt[j];
                r += (cj > my) || (cj == my && j < t);
            }
            ord[r] = t;
        }
        __syncthreads();

#pragma unroll
        for (int i = 0; i < NF / 256; ++i) {
            const int n = t + i * 256;
            const int p = atomicAdd(&cursor[seg[n]], 1);
            perm[p] = n;
        }
    }
}

// ---------------- Kernel B ---------------------------------------------------
// One block per (rank, b, chunk); rank = descending segment size (static LPT).
// Blocks are dispatched in blockIdx order as CU slots free, so the biggest
// segments start first and the tail holds only the smallest items — the HW
// dispatcher provides the dynamic balancing, with zero atomic contention.
// Per item: wave-redundant shuffle stats (scores L2-resident, m ~ 16), then
// a weighted gather over the chunk's 1024 floats. Every x element read once.
__global__ __launch_bounds__(256) void k_pool(const float* __restrict__ x,
                                              const float* __restrict__ scores,
                                              const int* __restrict__ offs,
                                              const int* __restrict__ perm,
                                              const int* __restrict__ ord,
                                              float* __restrict__ out) {
    __shared__ int   sm_row[TILE];
    __shared__ float sm_w[TILE];

    const int t     = threadIdx.x;
    const int lane  = t & 63;
    const int bid   = blockIdx.x;
    const int rank  = bid >> 4;            // 16 items (4 b x 4 chunks) per segment
    const int sub   = bid & 15;
    const int b     = sub >> 2;
    const int chunk = sub & 3;
    const int c     = ord[rank];

    const int off0 = offs[c];
    const int m    = offs[c + 1] - off0;
    const float* sb = scores + b * NF;

    // ---- per-wave redundant segment stats (no barriers) ----
    float pm = -INFINITY;
    for (int k = lane; k < m; k += 64)
        pm = fmaxf(pm, sb[perm[off0 + k]]);
#pragma unroll
    for (int off = 32; off >= 1; off >>= 1)
        pm = fmaxf(pm, __shfl_xor(pm, off, 64));
    const float smax = pm;

    float ps = 0.f;
    for (int k = lane; k < m; k += 64)
        ps += expf(sb[perm[off0 + k]] - smax);
#pragma unroll
    for (int off = 32; off >= 1; off >>= 1)
        ps += __shfl_xor(ps, off, 64);
    const float rden = 1.0f / ps;

    // ---- weighted gather over this chunk ----
    float4 acc0 = make_float4(0.f, 0.f, 0.f, 0.f);
    float4 acc1 = make_float4(0.f, 0.f, 0.f, 0.f);
    const float4* xb = (const float4*)x + (size_t)b * NF * (ROW / 4)
                     + (size_t)chunk * (CHF / 4) + t;

    for (int base = 0; base < m; base += TILE) {
        const int mt = min(TILE, m - base);
        __syncthreads();                       // protect LDS reuse across tiles
        if (t < mt) {
            const int r = perm[off0 + base + t];
            sm_row[t] = r;
            sm_w[t]   = expf(sb[r] - smax) * rden;
        }
        __syncthreads();

        int k = 0;
        for (; k + 2 <= mt; k += 2) {
            const float w0 = sm_w[k];
            const float w1 = sm_w[k + 1];
            const float4 v0 = xb[(size_t)sm_row[k]     * (ROW / 4)];
            const float4 v1 = xb[(size_t)sm_row[k + 1] * (ROW / 4)];
            acc0.x += w0 * v0.x; acc0.y += w0 * v0.y;
            acc0.z += w0 * v0.z; acc0.w += w0 * v0.w;
            acc1.x += w1 * v1.x; acc1.y += w1 * v1.y;
            acc1.z += w1 * v1.z; acc1.w += w1 * v1.w;
        }
        if (k < mt) {
            const float w0 = sm_w[k];
            const float4 v0 = xb[(size_t)sm_row[k] * (ROW / 4)];
            acc0.x += w0 * v0.x; acc0.y += w0 * v0.y;
            acc0.z += w0 * v0.z; acc0.w += w0 * v0.w;
        }
    }

    acc0.x += acc1.x; acc0.y += acc1.y; acc0.z += acc1.z; acc0.w += acc1.w;
    float4* op = (float4*)(out + (size_t)(b * NC + c) * ROW + (size_t)chunk * CHF);
    op[t] = acc0;
}

// ---------------------------------------------------------------------------
extern "C" void kernel_launch(void* const* d_in, const int* in_sizes, int n_in,
                              void* d_out, int out_size, void* d_ws, size_t ws_size,
                              hipStream_t stream) {
    const float* x    = (const float*)d_in[0];
    const float* W    = (const float*)d_in[1];
    const float* bias = (const float*)d_in[2];
    const int*   seg  = (const int*)d_in[3];
    float*       out  = (float*)d_out;

    float* scores = (float*)d_ws;              // B*NF floats
    int*   offs   = (int*)(scores + B * NF);   // NC+1 ints
    int*   perm   = offs + (NC + 1);           // NF ints
    int*   ord    = perm + NF;                 // NC ints

    k_scores_csr<<<B * NF / 4 + 1, 256, 0, stream>>>(x, W, bias, seg, scores,
                                                     offs, perm, ord);
    k_pool      <<<B * NC * CH,    256, 0, stream>>>(x, scores, offs, perm,
                                                     ord, out);
}

// Round 6
// 66.197 us; speedup vs baseline: 2.1819x; 1.4299x over previous
//
#include <hip/hip_runtime.h>
#include <math.h>

#define B   4
#define NF  4096
#define FM  32
#define H   128
#define NC  256
#define ROW (FM * H)      // 4096 floats per (b,n) row
#define RQ  (ROW / 4)     // 1024 float4 per row
#define MAXM 1024         // LDS member-list cap (realistic max m ~ 45)

// ---------------- Kernel A: CSR build (one block) ---------------------------
// offs[NC+1], perm[NF] : members of coarse segment c are perm[offs[c]..offs[c+1])
__global__ __launch_bounds__(256) void k_csr(const int* __restrict__ seg,
                                             int* __restrict__ offs,
                                             int* __restrict__ perm) {
    __shared__ int cnt[NC], sc[NC], cursor[NC];
    const int t = threadIdx.x;

    cnt[t] = 0;
    __syncthreads();
#pragma unroll
    for (int i = 0; i < NF / 256; ++i)
        atomicAdd(&cnt[seg[t + i * 256]], 1);
    __syncthreads();

    sc[t] = cnt[t];
    __syncthreads();
    for (int d = 1; d < NC; d <<= 1) {
        int v = (t >= d) ? sc[t - d] : 0;
        __syncthreads();
        sc[t] += v;
        __syncthreads();
    }
    const int ex = sc[t] - cnt[t];   // exclusive prefix
    offs[t]   = ex;
    cursor[t] = ex;
    if (t == 0) offs[NC] = NF;
    __syncthreads();

#pragma unroll
    for (int i = 0; i < NF / 256; ++i) {
        const int n = t + i * 256;
        perm[atomicAdd(&cursor[seg[n]], 1)] = n;
    }
}

// ---------------- Kernel B: fused score + online-softmax + gather -----------
// One block per (b, c). For each member row: stream the 16KB row into regs
// (4 float4/thread), compute its score via block-wide dot with W (one barrier
// per row, double-buffered LDS slots), then online-softmax accumulate the
// SAME registers. Every x element is read exactly ONCE across the grid.
__global__ __launch_bounds__(256) void k_fused(const float* __restrict__ x,
                                               const float* __restrict__ W,
                                               const float* __restrict__ bias,
                                               const int* __restrict__ offs,
                                               const int* __restrict__ perm,
                                               float* __restrict__ out) {
    __shared__ float red[8];          // 4 wave sums x 2 alternating slots
    __shared__ int   list[MAXM];

    const int t    = threadIdx.x;
    const int wid  = t >> 6;
    const int lane = t & 63;
    const int c    = blockIdx.x & (NC - 1);
    const int b    = blockIdx.x >> 8;

    const int off0 = offs[c];
    const int m    = offs[c + 1] - off0;

    for (int k = t; k < m && k < MAXM; k += 256)
        list[k] = perm[off0 + k];
    __syncthreads();

    // thread t owns float4 indices t, t+256, t+512, t+768 of each row;
    // element h = (4t) % 128 for all four -> one W fragment per thread.
    const float4 w4     = ((const float4*)W)[t & 31];
    const float  inv_fm = 1.0f / FM;
    const float  b0     = bias[0];
    const float4* xb    = (const float4*)x + (size_t)b * NF * RQ;

    float4 acc0 = {0,0,0,0}, acc1 = {0,0,0,0}, acc2 = {0,0,0,0}, acc3 = {0,0,0,0};
    float  mx = -INFINITY, denom = 0.f;

    float4 c0, c1, c2, c3;
    if (m > 0) {
        const float4* rp = xb + (size_t)list[0] * RQ + t;
        c0 = rp[0]; c1 = rp[256]; c2 = rp[512]; c3 = rp[768];
    }

    for (int r = 0; r < m; ++r) {
        // ---- software-pipelined load of next row ----
        float4 n0, n1, n2, n3;
        const bool more = (r + 1 < m);
        if (more) {
            const int nrow = (r + 1 < MAXM) ? list[r + 1] : perm[off0 + r + 1];
            const float4* np = xb + (size_t)nrow * RQ + t;
            n0 = np[0]; n1 = np[256]; n2 = np[512]; n3 = np[768];
        }

        // ---- block-wide dot: score of current row ----
        const float sx = c0.x + c1.x + c2.x + c3.x;
        const float sy = c0.y + c1.y + c2.y + c3.y;
        const float sz = c0.z + c1.z + c2.z + c3.z;
        const float sw = c0.w + c1.w + c2.w + c3.w;
        float p = sx * w4.x + sy * w4.y + sz * w4.z + sw * w4.w;
#pragma unroll
        for (int off = 32; off >= 1; off >>= 1)
            p += __shfl_xor(p, off, 64);
        if (lane == 0) red[(r & 1) * 4 + wid] = p;
        __syncthreads();
        const int sl = (r & 1) * 4;
        const float s = (red[sl] + red[sl + 1] + red[sl + 2] + red[sl + 3])
                        * inv_fm + b0;

        // ---- online softmax accumulate (rescale only when max grows) ----
        if (s > mx) {                       // block-uniform branch
            const float scale = __expf(mx - s);   // exp(-inf)=0 on first row
            denom *= scale;
            acc0.x *= scale; acc0.y *= scale; acc0.z *= scale; acc0.w *= scale;
            acc1.x *= scale; acc1.y *= scale; acc1.z *= scale; acc1.w *= scale;
            acc2.x *= scale; acc2.y *= scale; acc2.z *= scale; acc2.w *= scale;
            acc3.x *= scale; acc3.y *= scale; acc3.z *= scale; acc3.w *= scale;
            mx = s;
        }
        const float e = __expf(s - mx);
        denom += e;
        acc0.x += e * c0.x; acc0.y += e * c0.y; acc0.z += e * c0.z; acc0.w += e * c0.w;
        acc1.x += e * c1.x; acc1.y += e * c1.y; acc1.z += e * c1.z; acc1.w += e * c1.w;
        acc2.x += e * c2.x; acc2.y += e * c2.y; acc2.z += e * c2.z; acc2.w += e * c2.w;
        acc3.x += e * c3.x; acc3.y += e * c3.y; acc3.z += e * c3.z; acc3.w += e * c3.w;

        if (more) { c0 = n0; c1 = n1; c2 = n2; c3 = n3; }
    }

    const float inv = (denom > 0.f) ? (1.0f / denom) : 0.f;
    float4* op = (float4*)(out + (size_t)(b * NC + c) * ROW) + t;
    acc0.x *= inv; acc0.y *= inv; acc0.z *= inv; acc0.w *= inv;
    acc1.x *= inv; acc1.y *= inv; acc1.z *= inv; acc1.w *= inv;
    acc2.x *= inv; acc2.y *= inv; acc2.z *= inv; acc2.w *= inv;
    acc3.x *= inv; acc3.y *= inv; acc3.z *= inv; acc3.w *= inv;
    op[0] = acc0; op[256] = acc1; op[512] = acc2; op[768] = acc3;
}

// ---------------------------------------------------------------------------
extern "C" void kernel_launch(void* const* d_in, const int* in_sizes, int n_in,
                              void* d_out, int out_size, void* d_ws, size_t ws_size,
                              hipStream_t stream) {
    const float* x    = (const float*)d_in[0];
    const float* W    = (const float*)d_in[1];
    const float* bias = (const float*)d_in[2];
    const int*   seg  = (const int*)d_in[3];
    float*       out  = (float*)d_out;

    int* offs = (int*)d_ws;          // NC+1 ints
    int* perm = offs + (NC + 1);     // NF ints

    k_csr  <<<1,      256, 0, stream>>>(seg, offs, perm);
    k_fused<<<B * NC, 256, 0, stream>>>(x, W, bias, offs, perm, out);
}

// Round 7
// 57.927 us; speedup vs baseline: 2.4934x; 1.1428x over previous
//
#include <hip/hip_runtime.h>
#include <math.h>

#define B   4
#define NF  4096
#define FM  32
#define H   128
#define NC  256
#define ROW (FM * H)      // 4096 floats per (b,n) row
#define RQ  (ROW / 4)     // 1024 float4 per row

// One kernel. Block = (pair_rank, b); processes segments ord[pr] and
// ord[255-pr] (folded pairing by size -> near-constant per-block work).
// Preamble (parallel in every block, seg is L2-resident): histogram of
// segment sizes, rank by descending size, ordered compaction of the two
// member lists. Then the fused score + online-softmax + gather stream:
// each x element is read exactly once across the grid.
__global__ __launch_bounds__(256) void k_fused(const float* __restrict__ x,
                                               const float* __restrict__ W,
                                               const float* __restrict__ bias,
                                               const int* __restrict__ seg,
                                               float* __restrict__ out) {
    __shared__ __align__(16) int cnt[NC];
    __shared__ int   scn[256];
    __shared__ int   list[NF];       // 16 KB: member list of current segment
    __shared__ float red[8];         // 4 wave sums x 2 alternating slots
    __shared__ int   s_c[2];
    __shared__ int   s_m;

    const int t    = threadIdx.x;
    const int wid  = t >> 6;
    const int lane = t & 63;
    const int pr   = blockIdx.x >> 2;     // pair rank 0..127
    const int b    = blockIdx.x & 3;

    // ---- strip load of seg (thread t owns ints [16t, 16t+16)) + histogram ----
    int sv[16];
    cnt[t] = 0;
    __syncthreads();
    {
        const int4* s4 = (const int4*)seg;
#pragma unroll
        for (int k = 0; k < 4; ++k) {
            int4 v = s4[t * 4 + k];
            sv[k * 4 + 0] = v.x; sv[k * 4 + 1] = v.y;
            sv[k * 4 + 2] = v.z; sv[k * 4 + 3] = v.w;
        }
#pragma unroll
        for (int k = 0; k < 16; ++k)
            atomicAdd(&cnt[sv[k]], 1);
    }
    __syncthreads();

    // ---- rank of segment t by descending count (ties by id) ----
    {
        const int my = cnt[t];
        int r = 0;
        const int4* c4 = (const int4*)cnt;   // broadcast reads, no conflicts
#pragma unroll
        for (int j = 0; j < 64; ++j) {
            const int4 cv = c4[j];
            const int base = j * 4;
            r += (cv.x > my) || (cv.x == my && (base + 0) < t);
            r += (cv.y > my) || (cv.y == my && (base + 1) < t);
            r += (cv.z > my) || (cv.z == my && (base + 2) < t);
            r += (cv.w > my) || (cv.w == my && (base + 3) < t);
        }
        if (r == pr)       s_c[0] = t;     // big segment of the pair
        if (r == 255 - pr) s_c[1] = t;     // small segment of the pair
    }
    __syncthreads();

    const float4 w4     = ((const float4*)W)[t & 31];
    const float  inv_fm = 1.0f / FM;
    const float  b0     = bias[0];
    const float4* xb    = (const float4*)x + (size_t)b * NF * RQ;

    for (int half = 0; half < 2; ++half) {
        const int c = s_c[half];

        // ---- deterministic ordered compaction of members of c ----
        int loc = 0;
#pragma unroll
        for (int k = 0; k < 16; ++k) loc += (sv[k] == c);
        scn[t] = loc;
        __syncthreads();
        for (int d = 1; d < 256; d <<= 1) {
            int v = (t >= d) ? scn[t - d] : 0;
            __syncthreads();
            scn[t] += v;
            __syncthreads();
        }
        if (t == 255) s_m = scn[255];
        int pos = scn[t] - loc;              // exclusive prefix
        __syncthreads();
#pragma unroll
        for (int k = 0; k < 16; ++k)
            if (sv[k] == c) list[pos++] = t * 16 + k;
        __syncthreads();
        const int m = s_m;

        // ---- fused stream: score + online softmax + weighted accumulate ----
        // thread t owns float4 indices t, t+256, t+512, t+768 of each row;
        // h = (4t) % 128 for all four -> single W fragment per thread.
        float4 acc0 = {0,0,0,0}, acc1 = {0,0,0,0};
        float4 acc2 = {0,0,0,0}, acc3 = {0,0,0,0};
        float  mx = -INFINITY, denom = 0.f;

        float4 c0, c1, c2, c3;
        if (m > 0) {
            const float4* rp = xb + (size_t)list[0] * RQ + t;
            c0 = rp[0]; c1 = rp[256]; c2 = rp[512]; c3 = rp[768];
        }

        for (int r = 0; r < m; ++r) {
            // software-pipelined load of next row
            float4 n0, n1, n2, n3;
            const bool more = (r + 1 < m);
            if (more) {
                const float4* np = xb + (size_t)list[r + 1] * RQ + t;
                n0 = np[0]; n1 = np[256]; n2 = np[512]; n3 = np[768];
            }

            // block-wide dot: score of current row
            float p = (c0.x + c1.x + c2.x + c3.x) * w4.x
                    + (c0.y + c1.y + c2.y + c3.y) * w4.y
                    + (c0.z + c1.z + c2.z + c3.z) * w4.z
                    + (c0.w + c1.w + c2.w + c3.w) * w4.w;
#pragma unroll
            for (int off = 32; off >= 1; off >>= 1)
                p += __shfl_xor(p, off, 64);
            if (lane == 0) red[(r & 1) * 4 + wid] = p;
            __syncthreads();
            const int sl = (r & 1) * 4;
            const float s = (red[sl] + red[sl+1] + red[sl+2] + red[sl+3])
                            * inv_fm + b0;

            // online softmax accumulate (block-uniform branch)
            if (s > mx) {
                const float scale = __expf(mx - s);   // exp(-inf)=0 first row
                denom *= scale;
                acc0.x *= scale; acc0.y *= scale; acc0.z *= scale; acc0.w *= scale;
                acc1.x *= scale; acc1.y *= scale; acc1.z *= scale; acc1.w *= scale;
                acc2.x *= scale; acc2.y *= scale; acc2.z *= scale; acc2.w *= scale;
                acc3.x *= scale; acc3.y *= scale; acc3.z *= scale; acc3.w *= scale;
                mx = s;
            }
            const float e = __expf(s - mx);
            denom += e;
            acc0.x += e * c0.x; acc0.y += e * c0.y; acc0.z += e * c0.z; acc0.w += e * c0.w;
            acc1.x += e * c1.x; acc1.y += e * c1.y; acc1.z += e * c1.z; acc1.w += e * c1.w;
            acc2.x += e * c2.x; acc2.y += e * c2.y; acc2.z += e * c2.z; acc2.w += e * c2.w;
            acc3.x += e * c3.x; acc3.y += e * c3.y; acc3.z += e * c3.z; acc3.w += e * c3.w;

            if (more) { c0 = n0; c1 = n1; c2 = n2; c3 = n3; }
        }

        const float inv = (denom > 0.f) ? (1.0f / denom) : 0.f;
        float4* op = (float4*)(out + (size_t)(b * NC + c) * ROW) + t;
        acc0.x *= inv; acc0.y *= inv; acc0.z *= inv; acc0.w *= inv;
        acc1.x *= inv; acc1.y *= inv; acc1.z *= inv; acc1.w *= inv;
        acc2.x *= inv; acc2.y *= inv; acc2.z *= inv; acc2.w *= inv;
        acc3.x *= inv; acc3.y *= inv; acc3.z *= inv; acc3.w *= inv;
        op[0] = acc0; op[256] = acc1; op[512] = acc2; op[768] = acc3;

        __syncthreads();   // protect scn/list reuse in the second half
    }
}

// ---------------------------------------------------------------------------
extern "C" void kernel_launch(void* const* d_in, const int* in_sizes, int n_in,
                              void* d_out, int out_size, void* d_ws, size_t ws_size,
                              hipStream_t stream) {
    const float* x    = (const float*)d_in[0];
    const float* W    = (const float*)d_in[1];
    const float* bias = (const float*)d_in[2];
    const int*   seg  = (const int*)d_in[3];
    float*       out  = (float*)d_out;

    k_fused<<<(NC / 2) * B, 256, 0, stream>>>(x, W, bias, seg, out);
}

// Round 8
// 54.507 us; speedup vs baseline: 2.6499x; 1.0628x over previous
//
#include <hip/hip_runtime.h>
#include <math.h>

#define B   4
#define NF  4096
#define FM  32
#define H   128
#define NC  256
#define ROW (FM * H)      // 4096 floats per (b,n) row
#define RQ  (ROW / 4)     // 1024 float4 per row
#define NT  512           // threads per block (8 waves)
#define SPT (NF / NT)     // 8 seg values per thread

// One kernel. Block = (pair_rank, b), 512 threads; processes segments
// ord[pr] and ord[255-pr] (folded size-pairing -> near-constant work).
// Preamble per block (seg is tiny/L2-resident): histogram, rank by size,
// atomic-cursor compaction. Stream: 2-row batches, one barrier per batch,
// online softmax; every x element read exactly once across the grid.
__global__ __launch_bounds__(NT, 4) void k_fused(const float* __restrict__ x,
                                                 const float* __restrict__ W,
                                                 const float* __restrict__ bias,
                                                 const int* __restrict__ seg,
                                                 float* __restrict__ out) {
    __shared__ __align__(16) int cnt[NC];
    __shared__ int   list[NF];       // 16 KB member list of current segment
    __shared__ float redA[16];       // 8 wave sums x 2 parity slots
    __shared__ float redB[16];
    __shared__ int   s_c[2];
    __shared__ int   s_cur;

    const int t    = threadIdx.x;
    const int wid  = t >> 6;         // 0..7
    const int lane = t & 63;
    const int pr   = blockIdx.x >> 2;     // pair rank 0..127
    const int b    = blockIdx.x & 3;

    // ---- histogram of segment sizes (thread t owns ints [8t, 8t+8)) ----
    int sv[SPT];
    if (t < NC) cnt[t] = 0;
    __syncthreads();
    {
        const int4* s4 = (const int4*)seg;
#pragma unroll
        for (int k = 0; k < SPT / 4; ++k) {
            int4 v = s4[t * (SPT / 4) + k];
            sv[k * 4 + 0] = v.x; sv[k * 4 + 1] = v.y;
            sv[k * 4 + 2] = v.z; sv[k * 4 + 3] = v.w;
        }
#pragma unroll
        for (int k = 0; k < SPT; ++k)
            atomicAdd(&cnt[sv[k]], 1);
    }
    __syncthreads();

    // ---- rank segment t (t<256) by descending count, ties by id ----
    if (t < NC) {
        const int my = cnt[t];
        int r = 0;
        const int4* c4 = (const int4*)cnt;   // broadcast reads
#pragma unroll 16
        for (int j = 0; j < 64; ++j) {
            const int4 cv = c4[j];
            const int base = j * 4;
            r += (cv.x > my) || (cv.x == my && (base + 0) < t);
            r += (cv.y > my) || (cv.y == my && (base + 1) < t);
            r += (cv.z > my) || (cv.z == my && (base + 2) < t);
            r += (cv.w > my) || (cv.w == my && (base + 3) < t);
        }
        if (r == pr)       s_c[0] = t;     // big segment of the pair
        if (r == 255 - pr) s_c[1] = t;     // small segment of the pair
    }
    __syncthreads();

    // thread t owns float4 indices t and t+512 of each row; for both,
    // h = (4t) mod 128 -> single W fragment per thread.
    const float4 w4     = ((const float4*)W)[t & 31];
    const float  inv_fm = 1.0f / FM;
    const float  b0     = bias[0];
    const float4* xb    = (const float4*)x + (size_t)b * NF * RQ;

    for (int half = 0; half < 2; ++half) {
        const int c = s_c[half];
        const int m = cnt[c];

        // ---- atomic-cursor compaction of members of c ----
        if (t == 0) s_cur = 0;
        __syncthreads();
#pragma unroll
        for (int k = 0; k < SPT; ++k)
            if (sv[k] == c) list[atomicAdd(&s_cur, 1)] = t * SPT + k;
        __syncthreads();

        // ---- fused stream: 2-row batches ----
        float4 a0 = {0,0,0,0}, a1 = {0,0,0,0};
        float  mx = -INFINITY, denom = 0.f;

        float4 c0 = {0,0,0,0}, c1 = {0,0,0,0};
        float4 d0 = {0,0,0,0}, d1 = {0,0,0,0};
        if (m > 0) { const float4* p = xb + (size_t)list[0] * RQ + t; c0 = p[0]; c1 = p[NT]; }
        if (m > 1) { const float4* p = xb + (size_t)list[1] * RQ + t; d0 = p[0]; d1 = p[NT]; }

        int par = 0;
        for (int r = 0; r < m; r += 2, par ^= 1) {
            // software-pipelined load of the next two rows
            float4 n0, n1, n2, n3;
            const bool h2 = (r + 1 < m);
            const bool h3 = (r + 2 < m);
            const bool h4 = (r + 3 < m);
            if (h3) { const float4* p = xb + (size_t)list[r + 2] * RQ + t; n0 = p[0]; n1 = p[NT]; }
            if (h4) { const float4* p = xb + (size_t)list[r + 3] * RQ + t; n2 = p[0]; n3 = p[NT]; }

            // two independent block-wide dots, one barrier
            float p0 = (c0.x + c1.x) * w4.x + (c0.y + c1.y) * w4.y
                     + (c0.z + c1.z) * w4.z + (c0.w + c1.w) * w4.w;
            float p1 = (d0.x + d1.x) * w4.x + (d0.y + d1.y) * w4.y
                     + (d0.z + d1.z) * w4.z + (d0.w + d1.w) * w4.w;
#pragma unroll
            for (int off = 32; off >= 1; off >>= 1) {
                p0 += __shfl_xor(p0, off, 64);
                p1 += __shfl_xor(p1, off, 64);
            }
            if (lane == 0) { redA[par * 8 + wid] = p0; redB[par * 8 + wid] = p1; }
            __syncthreads();
            float s0 = 0.f, s1 = 0.f;
#pragma unroll
            for (int i = 0; i < 8; ++i) {
                s0 += redA[par * 8 + i];
                s1 += redB[par * 8 + i];
            }
            s0 = s0 * inv_fm + b0;
            s1 = h2 ? (s1 * inv_fm + b0) : -INFINITY;

            // online softmax accumulate, one rescale-check per pair
            const float m2 = fmaxf(s0, s1);
            if (m2 > mx) {
                const float sc = __expf(mx - m2);   // exp(-inf)=0 on first pair
                denom *= sc;
                a0.x *= sc; a0.y *= sc; a0.z *= sc; a0.w *= sc;
                a1.x *= sc; a1.y *= sc; a1.z *= sc; a1.w *= sc;
                mx = m2;
            }
            const float e0 = __expf(s0 - mx);
            const float e1 = h2 ? __expf(s1 - mx) : 0.f;
            denom += e0 + e1;
            a0.x += e0 * c0.x + e1 * d0.x; a0.y += e0 * c0.y + e1 * d0.y;
            a0.z += e0 * c0.z + e1 * d0.z; a0.w += e0 * c0.w + e1 * d0.w;
            a1.x += e0 * c1.x + e1 * d1.x; a1.y += e0 * c1.y + e1 * d1.y;
            a1.z += e0 * c1.z + e1 * d1.z; a1.w += e0 * c1.w + e1 * d1.w;

            if (h3) { c0 = n0; c1 = n1; }
            if (h4) { d0 = n2; d1 = n3; }
        }

        // ---- normalize + write ----
        const float inv = (denom > 0.f) ? (1.0f / denom) : 0.f;
        float4* op = (float4*)(out + (size_t)(b * NC + c) * ROW) + t;
        a0.x *= inv; a0.y *= inv; a0.z *= inv; a0.w *= inv;
        a1.x *= inv; a1.y *= inv; a1.z *= inv; a1.w *= inv;
        op[0]  = a0;
        op[NT] = a1;

        __syncthreads();   // protect list/s_cur/red reuse in second half
    }
}

// ---------------------------------------------------------------------------
extern "C" void kernel_launch(void* const* d_in, const int* in_sizes, int n_in,
                              void* d_out, int out_size, void* d_ws, size_t ws_size,
                              hipStream_t stream) {
    const float* x    = (const float*)d_in[0];
    const float* W    = (const float*)d_in[1];
    const float* bias = (const float*)d_in[2];
    const int*   seg  = (const int*)d_in[3];
    float*       out  = (float*)d_out;

    k_fused<<<(NC / 2) * B, NT, 0, stream>>>(x, W, bias, seg, out);
}

// Round 9
// 54.034 us; speedup vs baseline: 2.6731x; 1.0087x over previous
//
#include <hip/hip_runtime.h>
#include <math.h>

#define B   4
#define NF  4096
#define FM  32
#define H   128
#define NC  256
#define ROW (FM * H)      // 4096 floats per (b,n) row
#define RQ  (ROW / 4)     // 1024 float4 per row
#define NT  1024          // threads per block (16 waves)
#define SPT (NF / NT)     // 4 seg values per thread

// One kernel. Block = (pair_rank, b), 1024 threads; processes segments
// ord[pr] and ord[255-pr] (folded size-pairing -> near-constant work).
// 512 blocks = 2 blocks/CU = 32 waves/CU (max occupancy; needs VGPR<=64,
// hence thread owns exactly ONE float4 per row and launch_bounds(1024,8)).
// Preamble per block (seg is tiny/L2-resident): histogram, rank by size,
// atomic-cursor compaction. Stream: 2-row batches, one barrier per batch,
// online softmax; every x element read exactly once across the grid.
__global__ __launch_bounds__(NT, 8) void k_fused(const float* __restrict__ x,
                                                 const float* __restrict__ W,
                                                 const float* __restrict__ bias,
                                                 const int* __restrict__ seg,
                                                 float* __restrict__ out) {
    __shared__ __align__(16) int cnt[NC];
    __shared__ int   list[NF];       // 16 KB member list of current segment
    __shared__ float redA[32];       // 16 wave sums x 2 parity slots
    __shared__ float redB[32];
    __shared__ int   s_c[2];
    __shared__ int   s_cur;

    const int t    = threadIdx.x;
    const int wid  = t >> 6;         // 0..15
    const int lane = t & 63;
    const int pr   = blockIdx.x >> 2;     // pair rank 0..127
    const int b    = blockIdx.x & 3;

    // ---- histogram of segment sizes (thread t owns ints [4t, 4t+4)) ----
    int sv[SPT];
    if (t < NC) cnt[t] = 0;
    __syncthreads();
    {
        const int4 v = ((const int4*)seg)[t];
        sv[0] = v.x; sv[1] = v.y; sv[2] = v.z; sv[3] = v.w;
#pragma unroll
        for (int k = 0; k < SPT; ++k)
            atomicAdd(&cnt[sv[k]], 1);
    }
    __syncthreads();

    // ---- rank segment t (t<256) by descending count, ties by id ----
    if (t < NC) {
        const int my = cnt[t];
        int r = 0;
        const int4* c4 = (const int4*)cnt;   // broadcast reads
#pragma unroll 16
        for (int j = 0; j < 64; ++j) {
            const int4 cv = c4[j];
            const int base = j * 4;
            r += (cv.x > my) || (cv.x == my && (base + 0) < t);
            r += (cv.y > my) || (cv.y == my && (base + 1) < t);
            r += (cv.z > my) || (cv.z == my && (base + 2) < t);
            r += (cv.w > my) || (cv.w == my && (base + 3) < t);
        }
        if (r == pr)       s_c[0] = t;     // big segment of the pair
        if (r == 255 - pr) s_c[1] = t;     // small segment of the pair
    }
    __syncthreads();

    // thread t owns float4 index t of each row; h = (4t) mod 128 ->
    // single W fragment per thread.
    const float4 w4     = ((const float4*)W)[t & 31];
    const float  inv_fm = 1.0f / FM;
    const float  b0     = bias[0];
    const float4* xb    = (const float4*)x + (size_t)b * NF * RQ;

    for (int half = 0; half < 2; ++half) {
        const int c = s_c[half];
        const int m = cnt[c];

        // ---- atomic-cursor compaction of members of c ----
        if (t == 0) s_cur = 0;
        __syncthreads();
#pragma unroll
        for (int k = 0; k < SPT; ++k)
            if (sv[k] == c) list[atomicAdd(&s_cur, 1)] = t * SPT + k;
        __syncthreads();

        // ---- fused stream: 2-row batches, one barrier per batch ----
        float4 a0 = {0,0,0,0};
        float  mx = -INFINITY, denom = 0.f;

        float4 c0 = {0,0,0,0}, d0 = {0,0,0,0};
        if (m > 0) c0 = *(xb + (size_t)list[0] * RQ + t);
        if (m > 1) d0 = *(xb + (size_t)list[1] * RQ + t);

        int par = 0;
        for (int r = 0; r < m; r += 2, par ^= 1) {
            // software-pipelined load of the next two rows
            float4 n0, n2;
            const bool h2 = (r + 1 < m);
            const bool h3 = (r + 2 < m);
            const bool h4 = (r + 3 < m);
            if (h3) n0 = *(xb + (size_t)list[r + 2] * RQ + t);
            if (h4) n2 = *(xb + (size_t)list[r + 3] * RQ + t);

            // two independent block-wide dots, one barrier
            float p0 = c0.x * w4.x + c0.y * w4.y + c0.z * w4.z + c0.w * w4.w;
            float p1 = d0.x * w4.x + d0.y * w4.y + d0.z * w4.z + d0.w * w4.w;
#pragma unroll
            for (int off = 32; off >= 1; off >>= 1) {
                p0 += __shfl_xor(p0, off, 64);
                p1 += __shfl_xor(p1, off, 64);
            }
            if (lane == 0) { redA[par * 16 + wid] = p0; redB[par * 16 + wid] = p1; }
            __syncthreads();
            float s0 = 0.f, s1 = 0.f;
#pragma unroll
            for (int i = 0; i < 16; ++i) {
                s0 += redA[par * 16 + i];
                s1 += redB[par * 16 + i];
            }
            s0 = s0 * inv_fm + b0;
            s1 = h2 ? (s1 * inv_fm + b0) : -INFINITY;

            // online softmax accumulate, one rescale-check per pair
            const float m2 = fmaxf(s0, s1);
            if (m2 > mx) {
                const float sc = __expf(mx - m2);   // exp(-inf)=0 on first pair
                denom *= sc;
                a0.x *= sc; a0.y *= sc; a0.z *= sc; a0.w *= sc;
                mx = m2;
            }
            const float e0 = __expf(s0 - mx);
            const float e1 = h2 ? __expf(s1 - mx) : 0.f;
            denom += e0 + e1;
            a0.x += e0 * c0.x + e1 * d0.x;
            a0.y += e0 * c0.y + e1 * d0.y;
            a0.z += e0 * c0.z + e1 * d0.z;
            a0.w += e0 * c0.w + e1 * d0.w;

            if (h3) c0 = n0;
            if (h4) d0 = n2;
        }

        // ---- normalize + write ----
        const float inv = (denom > 0.f) ? (1.0f / denom) : 0.f;
        float4* op = (float4*)(out + (size_t)(b * NC + c) * ROW);
        a0.x *= inv; a0.y *= inv; a0.z *= inv; a0.w *= inv;
        op[t] = a0;

        __syncthreads();   // protect list/s_cur/red reuse in second half
    }
}

// ---------------------------------------------------------------------------
extern "C" void kernel_launch(void* const* d_in, const int* in_sizes, int n_in,
                              void* d_out, int out_size, void* d_ws, size_t ws_size,
                              hipStream_t stream) {
    const float* x    = (const float*)d_in[0];
    const float* W    = (const float*)d_in[1];
    const float* bias = (const float*)d_in[2];
    const int*   seg  = (const int*)d_in[3];
    float*       out  = (float*)d_out;

    k_fused<<<(NC / 2) * B, NT, 0, stream>>>(x, W, bias, seg, out);
}